// Round 13
// baseline (223.107 us; speedup 1.0000x reference)
//
#include <hip/hip_runtime.h>
#include <math.h>

#define NSTEP  730
#define NGRID  1500
#define LENF   15
#define PRECS  1e-5f
#define CH     16
#define NCHUNK 46                 // 45 full chunks + tail of 10
#define XROWDW 32                 // padded LDS x row: 8 grids * 4 dw
#define QROW   516                // 128 float4 = 512 dw + 4 pad
#define OTW    41                 // out-tile row: 40 + 1 pad

// fast x^y for x in (0,1], y in [1,6]: v_log_f32 + v_mul + v_exp_f32.
// (__powf lowers to the PRECISE __ocml_pow_f32 — the R0-R11 hidden cost.)
static __device__ __forceinline__ float fast_pow01(float x, float y) {
    return __builtin_amdgcn_exp2f(y * __builtin_amdgcn_logf(x));
}

// Block = 1 wave, 8 grids = 2 independent chains per lane (A: b*8+gl,
// B: A+4), 188 blocks. Two lean scalar chains interleave to fill the
// dep-latency stalls exposed once pow became 3 ops. R12 flow otherwise:
// chunked x staging, deferred mu-reduce via qbuf, ring conv, coalesced
// write-once stores. Single wave: lgkm waits, no barriers.
__global__ __launch_bounds__(64, 1)
void hbv_scan_kernel(const float* __restrict__ x,       // (730,1500,3)
                     const float* __restrict__ params,  // (1500,12,16)
                     const float* __restrict__ rtwts,   // (1500,2)
                     float* __restrict__ out)           // (730,1500,5)
{
    __shared__ float xbuf[CH*XROWDW];   //  2.0 KB
    __shared__ float qbuf[CH*QROW];     // 33.0 KB
    __shared__ float ring[8*32];        //  1.0 KB (conv history per grid)
    __shared__ float outtile[CH*OTW];   //  2.6 KB  (total ~38.6 KB)

    const int lane = threadIdx.x;
    const int gl = lane >> 4, m = lane & 15;
    const int b  = blockIdx.x;
    const int gA = b*8 + gl;                  // ≤ 1499 always
    const int gB = gA + 4;                    // phantom 1500..1503 for b=187
    const int gBc = (gB < NGRID) ? gB : (NGRID-1);
    const float inv16 = 1.f/16.f;

    // zero conv ring (slots for t<0 must read 0)
    #pragma unroll
    for (int i = 0; i < 4; ++i) ring[lane + 64*i] = 0.f;

    // ---- staging maps: 384 dw/chunk = 6 per lane (exact) ----
    int rbase[6], gcol[6], lslot[6];
    #pragma unroll
    for (int j = 0; j < 6; ++j) {
        const int idx = lane + 64*j;
        const int r = idx/24, rem = idx - 24*r;
        const int g8 = rem/3, ch = rem - 3*g8;
        rbase[j] = r;
        const int gc = b*24 + g8*3 + ch;
        gcol[j] = (gc < 4500) ? gc : (4497 + ch);   // phantom -> grid 1499
        lslot[j] = r*XROWDW + g8*4 + ch;
    }
    // preload chunk 0 (issue early; latency hides under setup)
    float stg[6];
    #pragma unroll
    for (int j = 0; j < 6; ++j) stg[j] = x[rbase[j]*4500 + gcol[j]];

    // ---- scaled parameters for both chains ----
    const float lo[12] = {1.f, 50.f, 0.05f, 0.01f, 0.001f, 0.2f, 0.f, 0.f, -2.5f, 0.5f, 0.f, 0.f};
    const float hi[12] = {6.f, 1000.f, 0.9f, 0.5f, 0.2f, 1.f, 10.f, 100.f, 2.5f, 10.f, 0.1f, 0.2f};
    float pA[12], pB[12];
    #pragma unroll
    for (int i = 0; i < 12; ++i) {
        pA[i] = lo[i] + params[(gA*12  + i)*16 + m] * (hi[i] - lo[i]);
        pB[i] = lo[i] + params[(gBc*12 + i)*16 + m] * (hi[i] - lo[i]);
    }
    const float ApBETA=pA[0], ApFC=pA[1], ApK1=pA[3], ApK2=pA[4], ApPERC=pA[6],
                ApTT=pA[8], ApCFMAX=pA[9], ApCWH=pA[11];
    const float AinvFC=1.f/ApFC, AinvLPFC=1.f/(pA[5]*ApFC);
    const float ArefCoef=pA[10]*ApCFMAX, AnegCMTT=-ApCFMAX*ApTT, ArefCTT=ArefCoef*ApTT;
    const float AoneMinusK0=1.f-pA[2], AK0UZL=pA[2]*pA[7];
    const float BpBETA=pB[0], BpFC=pB[1], BpK1=pB[3], BpK2=pB[4], BpPERC=pB[6],
                BpTT=pB[8], BpCFMAX=pB[9], BpCWH=pB[11];
    const float BinvFC=1.f/BpFC, BinvLPFC=1.f/(pB[5]*BpFC);
    const float BrefCoef=pB[10]*BpCFMAX, BnegCMTT=-BpCFMAX*BpTT, BrefCTT=BrefCoef*BpTT;
    const float BoneMinusK0=1.f-pB[2], BK0UZL=pB[2]*pB[7];

    // ---- routing weights for both grids (one-time; precise libm) ----
    float wqA[LENF], wqB[LENF];
    {
        auto mkw = [&](int g, float* wq) {
            const float ta  = rtwts[g*2+0] * 2.9f;
            const float tbv = rtwts[g*2+1] * 6.5f;
            const float aa = fmaxf(ta, 0.f) + 0.1f;
            const float th = fmaxf(tbv, 0.f) + 0.5f;
            const float c0v = expf(-lgammaf(aa)) * powf(th, -aa);
            float wsum = 0.f;
            #pragma unroll
            for (int k = 0; k < LENF; ++k) {
                const float tt = (float)k + 0.5f;
                wq[k] = c0v * powf(tt, aa-1.f) * expf(-tt/th);
                wsum += wq[k];
            }
            const float ws = inv16 / wsum;
            #pragma unroll
            for (int k = 0; k < LENF; ++k) wq[k] *= ws;
        };
        mkw(gA, wqA);
        mkw(gBc, wqB);
    }

    // ---- store maps: 640 dw/chunk = 10 per lane ----
    int st_o[10], st_g[10], st_ok[10];
    #pragma unroll
    for (int j = 0; j < 10; ++j) {
        const int idx = lane + 64*j;
        const int tt = idx/40, cl = idx - 40*tt;
        st_o[j] = tt*OTW + cl;
        st_g[j] = tt*7500 + cl;
        st_ok[j] = (b*40 + cl < 7500);            // suppress phantom cols
    }

    float ASP=0.001f, AMW=0.001f, ASM=0.001f, ASUZ=0.001f, ASLZ=0.001f;
    float BSP=0.001f, BMW=0.001f, BSM=0.001f, BSUZ=0.001f, BSLZ=0.001f;

    for (int c = 0; c < NCHUNK; ++c) {
        const int nstep = (c == NCHUNK-1) ? (NSTEP - (NCHUNK-1)*CH) : CH;

        // commit staged x, then issue next chunk's loads (hide HBM latency)
        #pragma unroll
        for (int j = 0; j < 6; ++j) xbuf[lslot[j]] = stg[j];
        asm volatile("s_waitcnt lgkmcnt(0)" ::: "memory");
        if (c+1 < NCHUNK) {
            #pragma unroll
            for (int j = 0; j < 6; ++j) {
                int rr = (c+1)*CH + rbase[j];
                rr = (rr < NSTEP) ? rr : (NSTEP-1);   // clamp tail rows
                stg[j] = x[rr*4500 + gcol[j]];
            }
        }

        // ---- scan: 16 steps, two independent chains interleaved ----
        #pragma unroll
        for (int s = 0; s < CH; ++s) {
            const float4 xa = *(const float4*)&xbuf[s*XROWDW + gl*4];
            const float4 xb = *(const float4*)&xbuf[s*XROWDW + 16 + gl*4];

            // ===== chain A =====
            {
                const float Pm = xa.x, Tm = xa.y, Em = xa.z;
                const float RAIN    = (Tm >= ApTT) ? Pm : 0.f;
                const float SNOW    = Pm - RAIN;
                const float meltcap = fmaxf(fmaf(ApCFMAX, Tm, AnegCMTT), 0.f);
                const float refcap  = fmaxf(fmaf(-ArefCoef, Tm, ArefCTT), 0.f);
                const float SP1 = ASP + SNOW;
                const float melt = fminf(meltcap, SP1);
                const float MW1 = AMW + melt;
                const float refreeze = fminf(refcap, MW1);
                const float SP2 = SP1 - melt + refreeze;
                const float MW2 = MW1 - refreeze;
                const float tosoil = fmaxf(fmaf(-ApCWH, SP2, MW2), 0.f);
                ASP = SP2;
                AMW = MW2 - tosoil;
                const float sw = fminf(fast_pow01(ASM * AinvFC, ApBETA), 1.f);
                const float rt = RAIN + tosoil;
                const float recharge = rt * sw;
                const float SM1 = fmaf(rt, 1.f - sw, ASM);
                const float SM2 = fminf(SM1, ApFC);
                const float excess = SM1 - SM2;
                const float evap = fminf(SM2 * AinvLPFC, 1.f);
                const float ETact = fminf(SM2, Em * evap);
                ASM = fmaxf(SM2 - ETact, PRECS);
                const float SUZ1 = ASUZ + recharge + excess;
                const float SUZ2 = fmaxf(SUZ1 - ApPERC, 0.f);
                const float PERC = SUZ1 - SUZ2;
                const float SUZ3 = fminf(SUZ2, fmaf(SUZ2, AoneMinusK0, AK0UZL));
                const float Q0 = SUZ2 - SUZ3;
                const float Q1 = ApK1 * SUZ3;
                ASUZ = SUZ3 - Q1;
                const float SLZ1 = ASLZ + PERC;
                const float Q2 = ApK2 * SLZ1;
                ASLZ = SLZ1 - Q2;
                *(float4*)&qbuf[s*QROW + lane*4] = make_float4(Q0, Q1, Q2, ETact);
            }
            // ===== chain B =====
            {
                const float Pm = xb.x, Tm = xb.y, Em = xb.z;
                const float RAIN    = (Tm >= BpTT) ? Pm : 0.f;
                const float SNOW    = Pm - RAIN;
                const float meltcap = fmaxf(fmaf(BpCFMAX, Tm, BnegCMTT), 0.f);
                const float refcap  = fmaxf(fmaf(-BrefCoef, Tm, BrefCTT), 0.f);
                const float SP1 = BSP + SNOW;
                const float melt = fminf(meltcap, SP1);
                const float MW1 = BMW + melt;
                const float refreeze = fminf(refcap, MW1);
                const float SP2 = SP1 - melt + refreeze;
                const float MW2 = MW1 - refreeze;
                const float tosoil = fmaxf(fmaf(-BpCWH, SP2, MW2), 0.f);
                BSP = SP2;
                BMW = MW2 - tosoil;
                const float sw = fminf(fast_pow01(BSM * BinvFC, BpBETA), 1.f);
                const float rt = RAIN + tosoil;
                const float recharge = rt * sw;
                const float SM1 = fmaf(rt, 1.f - sw, BSM);
                const float SM2 = fminf(SM1, BpFC);
                const float excess = SM1 - SM2;
                const float evap = fminf(SM2 * BinvLPFC, 1.f);
                const float ETact = fminf(SM2, Em * evap);
                BSM = fmaxf(SM2 - ETact, PRECS);
                const float SUZ1 = BSUZ + recharge + excess;
                const float SUZ2 = fmaxf(SUZ1 - BpPERC, 0.f);
                const float PERC = SUZ1 - SUZ2;
                const float SUZ3 = fminf(SUZ2, fmaf(SUZ2, BoneMinusK0, BK0UZL));
                const float Q0 = SUZ2 - SUZ3;
                const float Q1 = BpK1 * SUZ3;
                BSUZ = SUZ3 - Q1;
                const float SLZ1 = BSLZ + PERC;
                const float Q2 = BpK2 * SLZ1;
                BSLZ = SLZ1 - Q2;
                *(float4*)&qbuf[s*QROW + 256 + lane*4] = make_float4(Q0, Q1, Q2, ETact);
            }
        }
        asm volatile("s_waitcnt lgkmcnt(0)" ::: "memory");

        // ---- epilogue: lane (gl,m) reduces tasks (gA,s=m) and (gB,s=m) ----
        const int t = c*CH + m;
        float a0=0,a1=0,a2=0,a3=0, e0=0,e1=0,e2=0,e3=0;
        if (m < nstep) {
            #pragma unroll
            for (int i = 0; i < 16; ++i) {
                const float4 v = *(const float4*)&qbuf[m*QROW + gl*64 + i*4];
                a0 += v.x; a1 += v.y; a2 += v.z; a3 += v.w;
            }
            #pragma unroll
            for (int i = 0; i < 16; ++i) {
                const float4 v = *(const float4*)&qbuf[m*QROW + 256 + gl*64 + i*4];
                e0 += v.x; e1 += v.y; e2 += v.z; e3 += v.w;
            }
            ring[gl*32 + (t & 31)]     = a0 + a1 + a2;
            ring[(gl+4)*32 + (t & 31)] = e0 + e1 + e2;
        }
        asm volatile("s_waitcnt lgkmcnt(0)" ::: "memory");
        if (m < nstep) {
            float accA = 0.f, accB = 0.f;
            #pragma unroll
            for (int k = 0; k < LENF; ++k) {
                accA += wqA[k] * ring[gl*32 + ((t - k) & 31)];
                accB += wqB[k] * ring[(gl+4)*32 + ((t - k) & 31)];
            }
            float* otA = &outtile[m*OTW + gl*5];
            otA[0]=accA; otA[1]=a0*inv16; otA[2]=a1*inv16; otA[3]=a2*inv16; otA[4]=a3*inv16;
            float* otB = &outtile[m*OTW + (gl+4)*5];
            otB[0]=accB; otB[1]=e0*inv16; otB[2]=e1*inv16; otB[3]=e2*inv16; otB[4]=e3*inv16;
        }
        asm volatile("s_waitcnt lgkmcnt(0)" ::: "memory");

        // ---- coalesced write-once store: 40 contiguous dwords/(t,block) ----
        {
            const int ndw = nstep*40;
            float* ob = out + c*CH*7500 + b*40;
            #pragma unroll
            for (int j = 0; j < 10; ++j) {
                const int idx = lane + 64*j;
                if (idx < ndw && st_ok[j]) ob[st_g[j]] = outtile[st_o[j]];
            }
        }
    }
}

extern "C" void kernel_launch(void* const* d_in, const int* in_sizes, int n_in,
                              void* d_out, int out_size, void* d_ws, size_t ws_size,
                              hipStream_t stream)
{
    const float* x      = (const float*)d_in[0];
    const float* params = (const float*)d_in[1];
    const float* rt     = (const float*)d_in[2];
    float* out = (float*)d_out;

    dim3 grid(188), block(64);   // ceil(1500/8) blocks, 1 wave each
    hipLaunchKernelGGL(hbv_scan_kernel, grid, block, 0, stream, x, params, rt, out);
}

// Round 14
// 61.083 us; speedup vs baseline: 3.6525x; 3.6525x over previous
//
#include <hip/hip_runtime.h>
#include <math.h>

#define NSTEP  730
#define NGRID  1500
#define LENF   15
#define PRECS  1e-5f
#define CH     16
#define NCHUNK 46                  // 45 full chunks + tail of 10
#define NPHASE (NCHUNK+3)          // 4-stage pipeline: fill/drain 3 phases
#define QROW   260                 // 64 float4 = 256 dw + 4 pad (16B-aligned rows)
#define OTW    21                  // out-tile row: 20 + 1 pad

// fast x^y for x in (0,1], y in [1,6]: v_log_f32 + v_mul + v_exp_f32.
static __device__ __forceinline__ float fast_pow01(float x, float y) {
    return __builtin_amdgcn_exp2f(y * __builtin_amdgcn_logf(x));
}

// Block = 256 threads = 4 waves = 4 pipeline stages over 4 grids, 375 blocks.
// The HBV step is a cascade of 3 independent recursions, so the serial chain
// is SPLIT ACROSS WAVES chunk-wise:
//   W0 snow(c):    (SP,MW) recursion from x -> rt = RAIN+tosoil
//   W1 soil(c-1):  SM recursion (pow chain) from rt,E -> (re, ETact)
//   W2 resp(c-2):  (SUZ,SLZ) recursion from re -> (Q0,Q1,Q2,ET) q-vectors
//   W3 epi(c-3):   mu-reduce + ring conv + coalesced store; stages x(c+1)
// Each wave has ~1/3 of the per-step issue AND critical path; phases sync
// with one __syncthreads (same count on every wave).
__global__ __launch_bounds__(256, 1)
void hbv_scan_kernel(const float* __restrict__ x,       // (730,1500,3)
                     const float* __restrict__ params,  // (1500,12,16)
                     const float* __restrict__ rtwts,   // (1500,2)
                     float* __restrict__ out)           // (730,1500,5)
{
    __shared__ float  xring[3*CH*16];    //  3.0 KB  (chunk c in slot c%3)
    __shared__ float  rtbuf[2*CH*64];    //  8.0 KB  (snow -> soil)
    __shared__ float2 soilbuf[2*CH*64];  // 16.0 KB  (soil -> resp: re, ET)
    __shared__ float  qbuf[2*CH*QROW];   // 32.5 KB  (resp -> epi)
    __shared__ float  outtile[CH*OTW];   //  1.3 KB
    __shared__ float  ring[4*64];        //  1.0 KB  (conv history per grid)

    const int tid  = threadIdx.x;
    const int wid  = tid >> 6;
    const int lane = tid & 63;
    const int gl = lane >> 4, m = lane & 15;
    const int b  = blockIdx.x;
    const int g  = b*4 + gl;
    const float inv16 = 1.f/16.f;

    // prestage chunk 0 (W3) + zero conv ring, then one uniform barrier
    if (wid == 3) {
        #pragma unroll
        for (int j = 0; j < 3; ++j) {
            const int idx = lane + 64*j;
            const int r = idx/12, rem = idx - 12*r;
            const int gi = rem/3, ch = rem - 3*gi;
            xring[r*16 + gi*4 + ch] = x[r*4500 + b*12 + gi*3 + ch];
        }
    }
    ring[tid & 255] = 0.f;
    __syncthreads();

    if (wid == 0) {
        // ================= W0: snow recursion =================
        const float pTT     = -2.5f + params[(g*12+8)*16+m]*5.f;
        const float pCFMAX  =  0.5f + params[(g*12+9)*16+m]*9.5f;
        const float pCFR    =          params[(g*12+10)*16+m]*0.1f;
        const float pCWH    =          params[(g*12+11)*16+m]*0.2f;
        const float refCoef = pCFR*pCFMAX;
        const float negCMTT = -pCFMAX*pTT;
        const float refCTT  = refCoef*pTT;
        float SP = 0.001f, MW = 0.001f;
        for (int p = 0; p < NPHASE; ++p) {
            if (p < NCHUNK) {
                const float* xb = &xring[(p%3)*CH*16 + gl*4];
                float* rb = &rtbuf[(p&1)*CH*64];
                #pragma unroll
                for (int s = 0; s < CH; ++s) {
                    const float2 PT = *(const float2*)(xb + s*16);   // broadcast
                    const float Pm = PT.x, Tm = PT.y;
                    const float RAIN    = (Tm >= pTT) ? Pm : 0.f;
                    const float SNOW    = Pm - RAIN;
                    const float meltcap = fmaxf(fmaf(pCFMAX, Tm, negCMTT), 0.f);
                    const float refcap  = fmaxf(fmaf(-refCoef, Tm, refCTT), 0.f);
                    const float SP1 = SP + SNOW;
                    const float melt = fminf(meltcap, SP1);
                    const float MW1 = MW + melt;
                    const float refreeze = fminf(refcap, MW1);
                    SP = SP1 - melt + refreeze;
                    const float MW2 = MW1 - refreeze;
                    const float tosoil = fmaxf(fmaf(-pCWH, SP, MW2), 0.f);
                    MW = MW2 - tosoil;
                    rb[s*64 + lane] = RAIN + tosoil;
                }
            }
            __syncthreads();
        }
    } else if (wid == 1) {
        // ================= W1: soil (SM) recursion =================
        const float pBETA = 1.f  + params[(g*12+0)*16+m]*5.f;
        const float pFC   = 50.f + params[(g*12+1)*16+m]*950.f;
        const float pLP   = 0.2f + params[(g*12+5)*16+m]*0.8f;
        const float invFC = 1.f/pFC, invLPFC = 1.f/(pLP*pFC);
        float SM = 0.001f;
        for (int p = 0; p < NPHASE; ++p) {
            if (p >= 1 && p-1 < NCHUNK) {
                const int c = p-1;
                const float* xe = &xring[(c%3)*CH*16 + gl*4 + 2];
                const float* rb = &rtbuf[(c&1)*CH*64];
                float2* sb = &soilbuf[(c&1)*CH*64];
                #pragma unroll
                for (int s = 0; s < CH; ++s) {
                    const float rt = rb[s*64 + lane];
                    const float Em = xe[s*16];                        // broadcast
                    const float sw = fminf(fast_pow01(SM*invFC, pBETA), 1.f);
                    const float recharge = rt*sw;
                    const float SM1 = fmaf(rt, 1.f - sw, SM);
                    const float SM2 = fminf(SM1, pFC);
                    const float excess = SM1 - SM2;
                    const float evap = fminf(SM2*invLPFC, 1.f);
                    const float ETact = fminf(SM2, Em*evap);
                    SM = fmaxf(SM2 - ETact, PRECS);
                    sb[s*64 + lane] = make_float2(recharge + excess, ETact);
                }
            }
            __syncthreads();
        }
    } else if (wid == 2) {
        // ================= W2: response (SUZ,SLZ) recursion =================
        const float pK0   = 0.05f  + params[(g*12+2)*16+m]*0.85f;
        const float pK1   = 0.01f  + params[(g*12+3)*16+m]*0.49f;
        const float pK2   = 0.001f + params[(g*12+4)*16+m]*0.199f;
        const float pPERC =          params[(g*12+6)*16+m]*10.f;
        const float pUZL  =          params[(g*12+7)*16+m]*100.f;
        const float oneMinusK0 = 1.f - pK0, K0UZL = pK0*pUZL;
        float SUZ = 0.001f, SLZ = 0.001f;
        for (int p = 0; p < NPHASE; ++p) {
            if (p >= 2 && p-2 < NCHUNK) {
                const int c = p-2;
                const float2* sb = &soilbuf[(c&1)*CH*64];
                float* qb = &qbuf[(c&1)*CH*QROW];
                #pragma unroll
                for (int s = 0; s < CH; ++s) {
                    const float2 rE = sb[s*64 + lane];
                    const float SUZ1 = SUZ + rE.x;
                    const float SUZ2 = fmaxf(SUZ1 - pPERC, 0.f);
                    const float PERC = SUZ1 - SUZ2;
                    const float SUZ3 = fminf(SUZ2, fmaf(SUZ2, oneMinusK0, K0UZL));
                    const float Q0 = SUZ2 - SUZ3;
                    const float Q1 = pK1 * SUZ3;
                    SUZ = SUZ3 - Q1;
                    const float SLZ1 = SLZ + PERC;
                    const float Q2 = pK2 * SLZ1;
                    SLZ = SLZ1 - Q2;
                    *(float4*)&qb[s*QROW + lane*4] = make_float4(Q0, Q1, Q2, rE.y);
                }
            }
            __syncthreads();
        }
    } else {
        // ================= W3: epilogue + x staging =================
        float wq[LENF];
        {
            const float ta  = rtwts[g*2+0] * 2.9f;
            const float tbv = rtwts[g*2+1] * 6.5f;
            const float aa = fmaxf(ta, 0.f) + 0.1f;
            const float th = fmaxf(tbv, 0.f) + 0.5f;
            const float c0v = expf(-lgammaf(aa)) * powf(th, -aa);
            float wsum = 0.f;
            #pragma unroll
            for (int k = 0; k < LENF; ++k) {
                const float tt = (float)k + 0.5f;
                wq[k] = c0v * powf(tt, aa-1.f) * expf(-tt/th);
                wsum += wq[k];
            }
            const float ws = inv16 / wsum;
            #pragma unroll
            for (int k = 0; k < LENF; ++k) wq[k] *= ws;
        }
        int rbase[3], bcol[3], lslot[3];
        #pragma unroll
        for (int j = 0; j < 3; ++j) {
            const int idx = lane + 64*j;
            const int r = idx/12, rem = idx - 12*r;
            const int gi = rem/3, ch = rem - 3*gi;
            rbase[j] = r;
            bcol[j]  = b*12 + gi*3 + ch;
            lslot[j] = r*16 + gi*4 + ch;
        }
        int st_o[5], st_g[5];
        #pragma unroll
        for (int j = 0; j < 5; ++j) {
            const int idx = lane + 64*j;
            const int tt = idx/20, cl = idx - 20*tt;
            st_o[j] = tt*OTW + cl;
            st_g[j] = tt*7500 + cl;
        }

        for (int p = 0; p < NPHASE; ++p) {
            // (a) issue next chunk's x loads early (hide HBM under epilogue)
            const bool do_stage = (p+1 < NCHUNK);
            float stg0=0.f, stg1=0.f, stg2=0.f;
            if (do_stage) {
                int r0 = (p+1)*CH + rbase[0]; r0 = (r0 < NSTEP) ? r0 : (NSTEP-1);
                int r1 = (p+1)*CH + rbase[1]; r1 = (r1 < NSTEP) ? r1 : (NSTEP-1);
                int r2 = (p+1)*CH + rbase[2]; r2 = (r2 < NSTEP) ? r2 : (NSTEP-1);
                stg0 = x[r0*4500 + bcol[0]];
                stg1 = x[r1*4500 + bcol[1]];
                stg2 = x[r2*4500 + bcol[2]];
            }
            // (b) epilogue for chunk q = p-3
            const int q = p - 3;
            if (q >= 0) {
                const int nstep = (q == NCHUNK-1) ? (NSTEP - (NCHUNK-1)*CH) : CH;
                const float* qb = &qbuf[(q&1)*CH*QROW];
                const int t = q*CH + m;
                float a0=0.f, a1=0.f, a2=0.f, a3=0.f;
                if (m < nstep) {
                    #pragma unroll
                    for (int i = 0; i < 16; ++i) {
                        const float4 v = *(const float4*)&qb[m*QROW + gl*64 + i*4];
                        a0 += v.x; a1 += v.y; a2 += v.z; a3 += v.w;
                    }
                    ring[gl*64 + (t & 63)] = a0 + a1 + a2;
                }
                asm volatile("s_waitcnt lgkmcnt(0)" ::: "memory");
                if (m < nstep) {
                    float acc = 0.f;
                    #pragma unroll
                    for (int k = 0; k < LENF; ++k)
                        acc += wq[k] * ring[gl*64 + ((t - k) & 63)];
                    float* ot = &outtile[m*OTW + gl*5];
                    ot[0] = acc;
                    ot[1] = a0*inv16; ot[2] = a1*inv16;
                    ot[3] = a2*inv16; ot[4] = a3*inv16;
                }
                asm volatile("s_waitcnt lgkmcnt(0)" ::: "memory");
                const int ndw = nstep*20;
                float* ob = out + q*CH*7500 + b*20;
                #pragma unroll
                for (int j = 0; j < 5; ++j) {
                    const int idx = lane + 64*j;
                    if (idx < ndw) ob[st_g[j]] = outtile[st_o[j]];
                }
            }
            // (c) commit staged x for chunk p+1 (visible after barrier)
            if (do_stage) {
                float* xd = &xring[((p+1)%3)*CH*16];
                xd[lslot[0]] = stg0; xd[lslot[1]] = stg1; xd[lslot[2]] = stg2;
            }
            __syncthreads();
        }
    }
}

extern "C" void kernel_launch(void* const* d_in, const int* in_sizes, int n_in,
                              void* d_out, int out_size, void* d_ws, size_t ws_size,
                              hipStream_t stream)
{
    const float* x      = (const float*)d_in[0];
    const float* params = (const float*)d_in[1];
    const float* rt     = (const float*)d_in[2];
    float* out = (float*)d_out;

    dim3 grid(NGRID / 4), block(256);
    hipLaunchKernelGGL(hbv_scan_kernel, grid, block, 0, stream, x, params, rt, out);
}